// Round 1
// baseline (129.689 us; speedup 1.0000x reference)
//
#include <hip/hip_runtime.h>

// x: (N=8, C=32, D=16, H=64, W=256) f32
// out: (N, C, HP=66, WP=259) f32
// PAD (W_l, W_r, H_t, H_b, D_f, D_b) = (1,2,1,1,0,1); pool K=3 S=2 along W.

#define NN 8
#define CC 32
#define DD 16
#define HH 64
#define WW 256
#define HP 66
#define WP 259

__global__ __launch_bounds__(256) void fused_pool_kernel(const float* __restrict__ x,
                                                         float* __restrict__ out) {
    const int bid = blockIdx.x;          // (n*C + c)*HP + hp
    const int hp  = bid % HP;
    const int nc  = bid / HP;
    const int t   = threadIdx.x;

    float* outrow = out + (size_t)bid * WP;

    if (hp == 0 || hp == HP - 1) {
        // padded H rows: everything (unpooled + x_p) is zero
        outrow[t] = 0.f;
        if (t < WP - WW) outrow[WW + t] = 0.f;
        return;
    }
    const int h = hp - 1;

    // q[w] = padded row, w in [0, WP); ls has 2 guard cells each side so all
    // neighbor reads q[w-2..w+2] stay in-bounds (masked logically by the
    // window-existence flags).
    __shared__ float ls[WP + 4];
    float* q = ls + 2;

    // one-time zeros: guards + padded W edges (d-loop only rewrites q[1..256])
    if (t < 2)  { ls[t] = 0.f; ls[WP + 2 + t] = 0.f; }
    if (t == 0) { q[0] = 0.f; q[WW + 1] = 0.f; q[WW + 2] = 0.f; }

    float acc0 = 0.f, acc1 = 0.f;
    const int w1 = WW + t;               // 256..258 for t<3

    const float* xrow = x + ((size_t)nc * DD * HH + (size_t)h) * WW;

    for (int d = 0; d < DD; ++d) {
        __syncthreads();                          // protect q from prev iter readers
        q[1 + t] = xrow[(size_t)d * HH * WW + t]; // coalesced 1 KiB row load
        __syncthreads();

        // ---- w = t ----
        {
            const int w = t;
            const float pv = q[w];
            bool hit;
            if (w & 1) {
                // single covering window, offset 1 (first-argmax semantics)
                hit = (pv > q[w - 1]) & (pv >= q[w + 1]);
            } else {
                const bool a = (w <= 2 * 128) & (pv >= q[w + 1]) & (pv >= q[w + 2]);
                const bool b = (w >= 2)       & (pv > q[w - 2]) & (pv > q[w - 1]);
                hit = a | b;
            }
            acc0 += pv + (hit ? pv / (1.0f + fabsf(pv)) : 0.f);
        }
        // ---- w = 256 + t (only t < 3) ----
        if (t < WP - WW) {
            const int w = w1;
            const float pv = q[w];
            bool hit;
            if (w & 1) {
                hit = (pv > q[w - 1]) & (pv >= q[w + 1]);
            } else {
                const bool a = (w <= 2 * 128) & (pv >= q[w + 1]) & (pv >= q[w + 2]);
                const bool b = (w >= 2)       & (pv > q[w - 2]) & (pv > q[w - 1]);
                hit = a | b;
            }
            acc1 += pv + (hit ? pv / (1.0f + fabsf(pv)) : 0.f);
        }
    }

    const float inv = 1.0f / 17.0f;      // mean over Dp=17 (zero d-slice included)
    outrow[t] = acc0 * inv;
    if (t < WP - WW) outrow[w1] = acc1 * inv;
}

extern "C" void kernel_launch(void* const* d_in, const int* in_sizes, int n_in,
                              void* d_out, int out_size, void* d_ws, size_t ws_size,
                              hipStream_t stream) {
    const float* x = (const float*)d_in[0];
    float* out = (float*)d_out;
    const int grid = NN * CC * HP;       // 16896 blocks, one per output row
    fused_pool_kernel<<<grid, 256, 0, stream>>>(x, out);
}

// Round 2
// 47.593 us; speedup vs baseline: 2.7250x; 2.7250x over previous
//
#include <hip/hip_runtime.h>

// x: (N=8, C=32, D=16, H=64, W=256) f32
// out: (N, C, HP=66, WP=259) f32
// PAD (W_l,W_r,H_t,H_b,D_f,D_b) = (1,2,1,1,0,1); MaxPool1d K=3 S=2 along W,
// softsign, MaxUnpool1d, + x_p, mean over Dp=17.
//
// Identities used:
//  - padded H rows (hp=0,65) and padded D slice contribute nothing -> out rows 0.
//  - scatter -> gather: w is written iff it is the first-argmax of a covering
//    window. odd w: hit = q[w]>q[w-1] && q[w]>=q[w+1]. even w:
//    hit = (q[w]>=q[w+1] && q[w]>=q[w+2]) || (w>=2 && q[w]>q[w-2] && q[w]>q[w-1]).
//  - q[0]=q[257]=q[258]=0 -> out columns {0,257,258} are exactly 0.
// One 64-lane wave per output row; lane l owns q[4l+1..4l+4] (aligned float4
// load of x[...,4l..4l+3]); neighbors via 3 shfls; no LDS, no barriers.

#define NN 8
#define CC 32
#define DD 16
#define HH 64
#define WW 256
#define HP 66
#define WP 259

__global__ __launch_bounds__(256) void fused_pool_kernel(const float* __restrict__ x,
                                                         float* __restrict__ out) {
    const int wid  = blockIdx.x * 4 + (threadIdx.x >> 6);  // global wave id = out row
    const int lane = threadIdx.x & 63;
    const int hp   = wid % HP;
    const int nc   = wid / HP;

    float* orow = out + (size_t)wid * WP;
    const int w0 = 4 * lane + 1;          // this lane's first output column

    if (hp == 0 || hp == HP - 1) {        // padded-H rows: all zero
        orow[w0] = 0.f; orow[w0 + 1] = 0.f; orow[w0 + 2] = 0.f; orow[w0 + 3] = 0.f;
        if (lane == 0) { orow[0] = 0.f; orow[WW + 1] = 0.f; orow[WW + 2] = 0.f; }
        return;
    }
    const int h = hp - 1;
    const float* xbase = x + (((size_t)nc * DD * HH) + h) * WW + 4 * lane;

    // Phase 1: all 16 depth rows into registers (independent loads in flight)
    float4 b[DD];
#pragma unroll
    for (int d = 0; d < DD; ++d)
        b[d] = *reinterpret_cast<const float4*>(xbase + (size_t)d * HH * WW);

    // Phase 2: hit tests + softsign + accumulate
    float a0 = 0.f, a1 = 0.f, a2 = 0.f, a3 = 0.f;
#pragma unroll
    for (int d = 0; d < DD; ++d) {
        const float b0 = b[d].x, b1 = b[d].y, b2 = b[d].z, b3 = b[d].w;
        float pm1 = __shfl_up(b3, 1, 64);        // q[4l]   (prev lane's b3)
        float np0 = __shfl_down(b0, 1, 64);      // q[4l+5] (next lane's b0)
        float np1 = __shfl_down(b1, 1, 64);      // q[4l+6] (next lane's b1)
        if (lane == 0)  pm1 = 0.f;               // q[0] is W-left pad
        if (lane == 63) { np0 = 0.f; np1 = 0.f; }// q[257],q[258] are W-right pad

        // w=4l+1 (odd)
        const bool h0 = (b0 > pm1) & (b0 >= b1);
        // w=4l+2 (even): windows at w and w-2 (both always exist here)
        const bool h1 = ((b1 >= b2) & (b1 >= b3)) | ((b1 > pm1) & (b1 > b0));
        // w=4l+3 (odd)
        const bool h2 = (b2 > b1) & (b2 >= b3);
        // w=4l+4 (even): max 256, window at w exists (<=256), window at w-2 exists
        const bool h3 = ((b3 >= np0) & (b3 >= np1)) | ((b3 > b1) & (b3 > b2));

        a0 += b0 + (h0 ? b0 * __builtin_amdgcn_rcpf(1.f + fabsf(b0)) : 0.f);
        a1 += b1 + (h1 ? b1 * __builtin_amdgcn_rcpf(1.f + fabsf(b1)) : 0.f);
        a2 += b2 + (h2 ? b2 * __builtin_amdgcn_rcpf(1.f + fabsf(b2)) : 0.f);
        a3 += b3 + (h3 ? b3 * __builtin_amdgcn_rcpf(1.f + fabsf(b3)) : 0.f);
    }

    const float inv = 1.0f / 17.0f;       // mean over Dp=17 (incl. zero D-slice)
    orow[w0]     = a0 * inv;
    orow[w0 + 1] = a1 * inv;
    orow[w0 + 2] = a2 * inv;
    orow[w0 + 3] = a3 * inv;
    if (lane == 0) { orow[0] = 0.f; orow[WW + 1] = 0.f; orow[WW + 2] = 0.f; }
}

extern "C" void kernel_launch(void* const* d_in, const int* in_sizes, int n_in,
                              void* d_out, int out_size, void* d_ws, size_t ws_size,
                              hipStream_t stream) {
    const float* x = (const float*)d_in[0];
    float* out = (float*)d_out;
    const int rows = NN * CC * HP;        // 16896 rows, 1 wave each, 4 waves/block
    fused_pool_kernel<<<rows / 4, 256, 0, stream>>>(x, out);
}